// Round 1
// baseline (6294.456 us; speedup 1.0000x reference)
//
#include <hip/hip_runtime.h>

#define N_NODES 100000
#define N_EDGES 800000
#define IN_CH   768
#define HIDC    512
#define NHEAD   4
#define DHEAD   128
#define NETYPE  5
#define OUT_CH  153

typedef _Float16 f16;
typedef __attribute__((ext_vector_type(2))) _Float16 f16x2;
typedef __attribute__((ext_vector_type(4))) _Float16 f16x4;
typedef __attribute__((ext_vector_type(8))) _Float16 f16x8;
typedef __attribute__((ext_vector_type(4))) float f32x4;

static inline int cdiv(int a, int b) { return (a + b - 1) / b; }

// ---------------- conversion kernels ----------------

__global__ __launch_bounds__(256) void k_cvt_f16(const float* __restrict__ in,
                                                 f16* __restrict__ out, long n) {
  long i = ((long)blockIdx.x * blockDim.x + threadIdx.x) * 4;
  if (i < n) {
    float4 v = *(const float4*)(in + i);
    f16x4 o = { (f16)v.x, (f16)v.y, (f16)v.z, (f16)v.w };
    *(f16x4*)(out + i) = o;
  }
}

// in: [In][Out] fp32  ->  out: [Out][In] f16  (B^T for the GEMM)
__global__ __launch_bounds__(256) void k_transpose_cvt(const float* __restrict__ in,
                                                       f16* __restrict__ out,
                                                       int In, int Out) {
  int idx = blockIdx.x * 256 + threadIdx.x;
  if (idx >= In * Out) return;
  int o = idx / In;
  int i = idx - o * In;
  out[idx] = (f16)in[i * Out + o];
}

__global__ __launch_bounds__(256) void k_comb_bias(const float* __restrict__ skip_b,
                                                   const float* __restrict__ conv_bias,
                                                   float* __restrict__ outb, int layer) {
  int c = blockIdx.x * 256 + threadIdx.x;
  if (c < HIDC) {
    float v = skip_b[c];
    for (int j = 0; j < NETYPE; j++) v += conv_bias[(layer * NETYPE + j) * HIDC + c];
    outb[c] = v;
  }
}

// ---------------- CSR build ----------------

__global__ __launch_bounds__(256) void k_hist(const int* __restrict__ dst,
                                              int* __restrict__ deg) {
  int e = blockIdx.x * 256 + threadIdx.x;
  if (e < N_EDGES) atomicAdd(&deg[dst[e]], 1);
}

__global__ __launch_bounds__(1024) void k_scan(const int* __restrict__ deg,
                                               int* __restrict__ rowptr) {
  __shared__ int sm[1024];
  __shared__ int carry_s;
  int tid = threadIdx.x;
  if (tid == 0) carry_s = 0;
  __syncthreads();
  for (int base = 0; base < N_NODES; base += 1024) {
    int v = (base + tid < N_NODES) ? deg[base + tid] : 0;
    sm[tid] = v;
    __syncthreads();
    for (int off = 1; off < 1024; off <<= 1) {
      int t = (tid >= off) ? sm[tid - off] : 0;
      __syncthreads();
      sm[tid] += t;
      __syncthreads();
    }
    if (base + tid < N_NODES) rowptr[base + tid] = carry_s + sm[tid] - v;
    int tot = sm[1023];
    __syncthreads();
    if (tid == 0) carry_s += tot;
    __syncthreads();
  }
  if (tid == 0) rowptr[N_NODES] = carry_s;
}

__global__ __launch_bounds__(256) void k_scatter(const int* __restrict__ src,
                                                 const int* __restrict__ dst,
                                                 const int* __restrict__ et,
                                                 int* __restrict__ cursor,
                                                 int* __restrict__ packed) {
  int e = blockIdx.x * 256 + threadIdx.x;
  if (e < N_EDGES) {
    int pos = atomicAdd(&cursor[dst[e]], 1);
    packed[pos] = src[e] | (et[e] << 27);
  }
}

// ---------------- GEMM: C[M,Nc] = A[M,K](f16) @ Bt[Nc,K]^T(f16) + bias ----------------
// 128x128 block tile, BK=32, 4 waves in 2x2, each wave 64x64 via 4x4 mfma 16x16x32.
// LDS rows padded to 40 halves (80 B, 16B-aligned; 2-way bank aliasing is free).

__global__ __launch_bounds__(256) void k_gemm(const f16* __restrict__ A,
                                              const f16* __restrict__ Bt,
                                              const float* __restrict__ bias,
                                              float* __restrict__ C,
                                              int M, int Nc, int K) {
  __shared__ f16 As[128 * 40];
  __shared__ f16 Bs[128 * 40];
  int tid = threadIdx.x;
  int bm = blockIdx.x * 128, bn = blockIdx.y * 128;
  int wave = tid >> 6, lane = tid & 63;
  int wm = (wave >> 1) * 64, wn = (wave & 1) * 64;
  int sr = tid >> 1, sq = (tid & 1) * 16;  // staging: row, col-quarter(16)
  int arow_ok = (bm + sr) < M;
  int brow_ok = (bn + sr) < Nc;
  const f16* aptr = A + (size_t)(bm + sr) * K + sq;
  const f16* bptr = Bt + (size_t)(bn + sr) * K + sq;
  int frow = lane & 15, fk = (lane >> 4) * 8;
  f32x4 acc[4][4] = {};

  for (int k0 = 0; k0 < K; k0 += 32) {
    uint4 av0 = {0, 0, 0, 0}, av1 = {0, 0, 0, 0};
    uint4 bv0 = {0, 0, 0, 0}, bv1 = {0, 0, 0, 0};
    if (arow_ok) {
      av0 = *(const uint4*)(aptr + k0);
      av1 = *(const uint4*)(aptr + k0 + 8);
    }
    if (brow_ok) {
      bv0 = *(const uint4*)(bptr + k0);
      bv1 = *(const uint4*)(bptr + k0 + 8);
    }
    __syncthreads();
    *(uint4*)(As + sr * 40 + sq) = av0;
    *(uint4*)(As + sr * 40 + sq + 8) = av1;
    *(uint4*)(Bs + sr * 40 + sq) = bv0;
    *(uint4*)(Bs + sr * 40 + sq + 8) = bv1;
    __syncthreads();
    f16x8 af[4], bf[4];
#pragma unroll
    for (int mi = 0; mi < 4; mi++)
      af[mi] = *(const f16x8*)(As + (wm + mi * 16 + frow) * 40 + fk);
#pragma unroll
    for (int ni = 0; ni < 4; ni++)
      bf[ni] = *(const f16x8*)(Bs + (wn + ni * 16 + frow) * 40 + fk);
#pragma unroll
    for (int mi = 0; mi < 4; mi++)
#pragma unroll
      for (int ni = 0; ni < 4; ni++)
        acc[mi][ni] = __builtin_amdgcn_mfma_f32_16x16x32_f16(af[mi], bf[ni],
                                                             acc[mi][ni], 0, 0, 0);
  }

  int ccol = lane & 15, crow = (lane >> 4) * 4;  // D: col=lane&15, row=(lane>>4)*4+r
#pragma unroll
  for (int mi = 0; mi < 4; mi++) {
#pragma unroll
    for (int r = 0; r < 4; r++) {
      int rg = bm + wm + mi * 16 + crow + r;
      if (rg < M) {
#pragma unroll
        for (int ni = 0; ni < 4; ni++) {
          int cg = bn + wn + ni * 16 + ccol;
          if (cg < Nc)
            C[(size_t)rg * Nc + cg] = acc[mi][ni][r] + (bias ? bias[cg] : 0.f);
        }
      }
    }
  }
}

// ---------------- attention scores: el/er per (node, head) ----------------
// wave w handles head w; lane l covers cols w*128 + 2l, 2l+1

__global__ __launch_bounds__(256) void k_attn(const float* __restrict__ feat,
                                              const float* __restrict__ al,
                                              const float* __restrict__ ar,
                                              float* __restrict__ el,
                                              float* __restrict__ er) {
  int node = blockIdx.x;
  int wv = threadIdx.x >> 6, lane = threadIdx.x & 63;
  float2 f = *(const float2*)(feat + (size_t)node * HIDC + wv * DHEAD + lane * 2);
  float2 a = *(const float2*)(al + wv * DHEAD + lane * 2);
  float2 b = *(const float2*)(ar + wv * DHEAD + lane * 2);
  float sl = f.x * a.x + f.y * a.y;
  float sr = f.x * b.x + f.y * b.y;
#pragma unroll
  for (int off = 32; off > 0; off >>= 1) {
    sl += __shfl_down(sl, off);
    sr += __shfl_down(sr, off);
  }
  if (lane == 0) {
    el[node * NHEAD + wv] = sl;
    er[node * NHEAD + wv] = sr;
  }
}

// ---------------- per-dst aggregation for one etype ----------------
// block = one dst node; wave w = head w; online softmax then weighted gather.

__global__ __launch_bounds__(256) void k_aggregate(const int* __restrict__ rowptr,
                                                   const int* __restrict__ packed,
                                                   const float* __restrict__ el,
                                                   const float* __restrict__ er,
                                                   const float* __restrict__ feat,
                                                   float* __restrict__ x_skip, int et) {
  int d = blockIdx.x;
  int beg = rowptr[d], end = rowptr[d + 1];
  if (beg == end) return;
  int wv = threadIdx.x >> 6, lane = threadIdx.x & 63;
  float erh = er[d * NHEAD + wv];
  float m = -1e30f, s = 0.f;
  for (int p = beg; p < end; ++p) {
    int pk = packed[p];
    if ((pk >> 27) != et) continue;
    int sn = pk & 0x07FFFFFF;
    float e = el[sn * NHEAD + wv] + erh;
    e = (e > 0.f) ? e : 0.2f * e;
    float nm = fmaxf(m, e);
    s = s * __expf(m - nm) + __expf(e - nm);
    m = nm;
  }
  if (s <= 0.f) return;  // no matching edges: contribution is exactly 0
  float inv = 1.f / s;
  int c = wv * DHEAD + lane * 2;
  float accx = 0.f, accy = 0.f;
  for (int p = beg; p < end; ++p) {
    int pk = packed[p];
    if ((pk >> 27) != et) continue;
    int sn = pk & 0x07FFFFFF;
    float e = el[sn * NHEAD + wv] + erh;
    e = (e > 0.f) ? e : 0.2f * e;
    float alpha = __expf(e - m) * inv;
    float2 f = *(const float2*)(feat + (size_t)sn * HIDC + c);
    accx += alpha * f.x;
    accy += alpha * f.y;
  }
  float2* xp = (float2*)(x_skip + (size_t)d * HIDC + c);
  float2 v = *xp;
  v.x += accx;
  v.y += accy;
  *xp = v;
}

// ---------------- batch norm ----------------

__global__ __launch_bounds__(256) void k_bn_reduce(const float* __restrict__ x,
                                                   float* __restrict__ gsum,
                                                   float* __restrict__ gsq) {
  int t = threadIdx.x;
  float sx = 0.f, sy = 0.f, qx = 0.f, qy = 0.f;
  for (int r = blockIdx.x; r < N_NODES; r += gridDim.x) {
    float2 v = *(const float2*)(x + (size_t)r * HIDC + t * 2);
    sx += v.x; sy += v.y;
    qx += v.x * v.x; qy += v.y * v.y;
  }
  atomicAdd(&gsum[t * 2], sx);
  atomicAdd(&gsum[t * 2 + 1], sy);
  atomicAdd(&gsq[t * 2], qx);
  atomicAdd(&gsq[t * 2 + 1], qy);
}

__global__ __launch_bounds__(256) void k_bn_final(const float* __restrict__ gsum,
                                                  const float* __restrict__ gsq,
                                                  const float* __restrict__ gamma,
                                                  const float* __restrict__ beta,
                                                  float* __restrict__ scale,
                                                  float* __restrict__ shift) {
  int c = blockIdx.x * 256 + threadIdx.x;
  if (c < HIDC) {
    float mu = gsum[c] * (1.f / N_NODES);
    float var = gsq[c] * (1.f / N_NODES) - mu * mu;
    float sc = gamma[c] * rsqrtf(var + 1e-5f);
    scale[c] = sc;
    shift[c] = beta[c] - mu * sc;
  }
}

// act==0: ELU, act==1: ReLU; writes f16 (next GEMM input)
__global__ __launch_bounds__(256) void k_bn_apply(const float* __restrict__ x,
                                                  const float* __restrict__ scale,
                                                  const float* __restrict__ shift,
                                                  f16* __restrict__ out, int act) {
  long i = ((long)blockIdx.x * blockDim.x + threadIdx.x) * 2;
  if (i >= (long)N_NODES * HIDC) return;
  int c = (int)(i & (HIDC - 1));
  float2 v = *(const float2*)(x + i);
  float a0 = scale[c] * v.x + shift[c];
  float a1 = scale[c + 1] * v.y + shift[c + 1];
  if (act == 0) {
    a0 = a0 > 0.f ? a0 : expm1f(a0);
    a1 = a1 > 0.f ? a1 : expm1f(a1);
  } else {
    a0 = fmaxf(a0, 0.f);
    a1 = fmaxf(a1, 0.f);
  }
  f16x2 o = { (f16)a0, (f16)a1 };
  *(f16x2*)(out + i) = o;
}

// ---------------- launch ----------------

extern "C" void kernel_launch(void* const* d_in, const int* in_sizes, int n_in,
                              void* d_out, int out_size, void* d_ws, size_t ws_size,
                              hipStream_t stream) {
  const float* x = (const float*)d_in[0];
  const int* src = (const int*)d_in[1];
  const int* dst = (const int*)d_in[2];
  const int* etype = (const int*)d_in[3];
  const float* W0 = (const float*)d_in[4];
  const float* W1 = (const float*)d_in[5];
  const float* attn_l = (const float*)d_in[6];
  const float* attn_r = (const float*)d_in[7];
  const float* conv_bias = (const float*)d_in[8];
  const float* skip_W0 = (const float*)d_in[9];
  const float* skip_b0 = (const float*)d_in[10];
  const float* skip_W1 = (const float*)d_in[11];
  const float* skip_b1 = (const float*)d_in[12];
  const float* norm_gamma = (const float*)d_in[13];
  const float* norm_beta = (const float*)d_in[14];
  const float* mlp_W1 = (const float*)d_in[15];
  const float* mlp_b1 = (const float*)d_in[16];
  const float* mlp_g = (const float*)d_in[17];
  const float* mlp_bt = (const float*)d_in[18];
  const float* mlp_W2 = (const float*)d_in[19];
  const float* mlp_b2 = (const float*)d_in[20];
  float* out = (float*)d_out;

  char* ws = (char*)d_ws;
  size_t off = 0;
  auto alloc = [&](size_t bytes) {
    void* p = ws + off;
    off = (off + bytes + 255) & ~(size_t)255;
    return p;
  };
  float* x_skip = (float*)alloc((size_t)N_NODES * HIDC * 4);
  float* feat   = (float*)alloc((size_t)N_NODES * HIDC * 4);
  f16*   hb     = (f16*)alloc((size_t)N_NODES * IN_CH * 2);
  float* el     = (float*)alloc((size_t)N_NODES * NHEAD * 4);
  float* er     = (float*)alloc((size_t)N_NODES * NHEAD * 4);
  int*   deg    = (int*)alloc((size_t)N_NODES * 4);
  int*   rowptr = (int*)alloc((size_t)(N_NODES + 1) * 4);
  int*   cursor = (int*)alloc((size_t)N_NODES * 4);
  int*   packed = (int*)alloc((size_t)N_EDGES * 4);
  f16* W0t  = (f16*)alloc((size_t)NETYPE * HIDC * IN_CH * 2);
  f16* W1t  = (f16*)alloc((size_t)NETYPE * HIDC * HIDC * 2);
  f16* sW0t = (f16*)alloc((size_t)HIDC * IN_CH * 2);
  f16* sW1t = (f16*)alloc((size_t)HIDC * HIDC * 2);
  f16* m1t  = (f16*)alloc((size_t)HIDC * HIDC * 2);
  f16* m2t  = (f16*)alloc((size_t)OUT_CH * HIDC * 2);
  float* bias0 = (float*)alloc(HIDC * 4);
  float* bias1 = (float*)alloc(HIDC * 4);
  float* gsum  = (float*)alloc(HIDC * 4);
  float* gsq   = (float*)alloc(HIDC * 4);
  float* scale = (float*)alloc(HIDC * 4);
  float* shift = (float*)alloc(HIDC * 4);

  // ---- CSR build ----
  hipMemsetAsync(deg, 0, (size_t)N_NODES * 4, stream);
  k_hist<<<cdiv(N_EDGES, 256), 256, 0, stream>>>(dst, deg);
  k_scan<<<1, 1024, 0, stream>>>(deg, rowptr);
  hipMemcpyAsync(cursor, rowptr, (size_t)N_NODES * 4, hipMemcpyDeviceToDevice, stream);
  k_scatter<<<cdiv(N_EDGES, 256), 256, 0, stream>>>(src, dst, etype, cursor, packed);

  // ---- weight conversion (B^T, f16) ----
  for (int j = 0; j < NETYPE; j++)
    k_transpose_cvt<<<cdiv(IN_CH * HIDC, 256), 256, 0, stream>>>(
        W0 + (size_t)j * IN_CH * HIDC, W0t + (size_t)j * HIDC * IN_CH, IN_CH, HIDC);
  for (int j = 0; j < NETYPE; j++)
    k_transpose_cvt<<<cdiv(HIDC * HIDC, 256), 256, 0, stream>>>(
        W1 + (size_t)j * HIDC * HIDC, W1t + (size_t)j * HIDC * HIDC, HIDC, HIDC);
  k_transpose_cvt<<<cdiv(IN_CH * HIDC, 256), 256, 0, stream>>>(skip_W0, sW0t, IN_CH, HIDC);
  k_transpose_cvt<<<cdiv(HIDC * HIDC, 256), 256, 0, stream>>>(skip_W1, sW1t, HIDC, HIDC);
  k_transpose_cvt<<<cdiv(HIDC * HIDC, 256), 256, 0, stream>>>(mlp_W1, m1t, HIDC, HIDC);
  k_transpose_cvt<<<cdiv(HIDC * OUT_CH, 256), 256, 0, stream>>>(mlp_W2, m2t, HIDC, OUT_CH);
  k_comb_bias<<<2, 256, 0, stream>>>(skip_b0, conv_bias, bias0, 0);
  k_comb_bias<<<2, 256, 0, stream>>>(skip_b1, conv_bias, bias1, 1);

  // ---- x -> f16 ----
  k_cvt_f16<<<cdiv(N_NODES * IN_CH / 4, 256), 256, 0, stream>>>(
      x, hb, (long)N_NODES * IN_CH);

  const int gm = cdiv(N_NODES, 128);

  for (int layer = 0; layer < 2; layer++) {
    int K = layer ? HIDC : IN_CH;
    const f16* skipt = layer ? sW1t : sW0t;
    const f16* Wt = layer ? W1t : W0t;
    const float* biasL = layer ? bias1 : bias0;

    // x_skip = hb @ skipW + (skip_b + sum_j conv_bias)
    k_gemm<<<dim3(gm, 4), 256, 0, stream>>>(hb, skipt, biasL, x_skip, N_NODES, HIDC, K);

    for (int j = 0; j < NETYPE; j++) {
      k_gemm<<<dim3(gm, 4), 256, 0, stream>>>(
          hb, Wt + (size_t)j * HIDC * K, nullptr, feat, N_NODES, HIDC, K);
      k_attn<<<N_NODES, 256, 0, stream>>>(
          feat, attn_l + ((size_t)layer * NETYPE + j) * NHEAD * DHEAD,
          attn_r + ((size_t)layer * NETYPE + j) * NHEAD * DHEAD, el, er);
      k_aggregate<<<N_NODES, 256, 0, stream>>>(rowptr, packed, el, er, feat, x_skip, j);
    }

    hipMemsetAsync(gsum, 0, HIDC * 4, stream);
    hipMemsetAsync(gsq, 0, HIDC * 4, stream);
    k_bn_reduce<<<512, 256, 0, stream>>>(x_skip, gsum, gsq);
    k_bn_final<<<2, 256, 0, stream>>>(gsum, gsq, norm_gamma + layer * HIDC,
                                      norm_beta + layer * HIDC, scale, shift);
    k_bn_apply<<<cdiv(N_NODES * HIDC / 2, 256), 256, 0, stream>>>(
        x_skip, scale, shift, hb, 0);
  }

  // ---- MLP head ----
  k_gemm<<<dim3(gm, 4), 256, 0, stream>>>(hb, m1t, mlp_b1, feat, N_NODES, HIDC, HIDC);
  hipMemsetAsync(gsum, 0, HIDC * 4, stream);
  hipMemsetAsync(gsq, 0, HIDC * 4, stream);
  k_bn_reduce<<<512, 256, 0, stream>>>(feat, gsum, gsq);
  k_bn_final<<<2, 256, 0, stream>>>(gsum, gsq, mlp_g, mlp_bt, scale, shift);
  k_bn_apply<<<cdiv(N_NODES * HIDC / 2, 256), 256, 0, stream>>>(feat, scale, shift, hb, 1);
  k_gemm<<<dim3(gm, cdiv(OUT_CH, 128)), 256, 0, stream>>>(
      hb, m2t, mlp_b2, out, N_NODES, OUT_CH, HIDC);
}

// Round 2
// 4625.341 us; speedup vs baseline: 1.3609x; 1.3609x over previous
//
#include <hip/hip_runtime.h>

#define N_NODES 100000
#define N_EDGES 800000
#define IN_CH   768
#define HIDC    512
#define NHEAD   4
#define DHEAD   128
#define NETYPE  5
#define OUT_CH  153
#define FEATW   1280   // 5 etypes x 256 cols (half of the heads)

typedef _Float16 f16;
typedef __attribute__((ext_vector_type(2))) _Float16 f16x2;
typedef __attribute__((ext_vector_type(4))) _Float16 f16x4;
typedef __attribute__((ext_vector_type(8))) _Float16 f16x8;
typedef __attribute__((ext_vector_type(4))) float f32x4;

static inline int cdiv(int a, int b) { return (a + b - 1) / b; }

// ---------------- conversion kernels ----------------

__global__ __launch_bounds__(256) void k_cvt_f16(const float* __restrict__ in,
                                                 f16* __restrict__ out, long n) {
  long i = ((long)blockIdx.x * blockDim.x + threadIdx.x) * 4;
  if (i < n) {
    float4 v = *(const float4*)(in + i);
    f16x4 o = { (f16)v.x, (f16)v.y, (f16)v.z, (f16)v.w };
    *(f16x4*)(out + i) = o;
  }
}

// in: [In][Out] fp32  ->  out: [Out][In] f16  (B^T for the GEMM)
__global__ __launch_bounds__(256) void k_transpose_cvt(const float* __restrict__ in,
                                                       f16* __restrict__ out,
                                                       int In, int Out) {
  int idx = blockIdx.x * 256 + threadIdx.x;
  if (idx >= In * Out) return;
  int o = idx / In;
  int i = idx - o * In;
  out[idx] = (f16)in[i * Out + o];
}

// W: [NE][K][HIDC] fp32 -> out: [NE*256][K] f16, out[j*256+c][k] = W[j][k][colOff+c]
__global__ __launch_bounds__(256) void k_transpose_stack(const float* __restrict__ W,
                                                         f16* __restrict__ out,
                                                         int K, int colOff) {
  int idx = blockIdx.x * 256 + threadIdx.x;
  if (idx >= NETYPE * 256 * K) return;
  int k = idx % K;
  int rc = idx / K;          // j*256 + c
  int j = rc >> 8, c = rc & 255;
  out[idx] = (f16)W[((size_t)j * K + k) * HIDC + colOff + c];
}

// wlr[row][k], row = j*8 + (isr?4:0) + h : projected attention vectors W_j . a
__global__ __launch_bounds__(256) void k_wlr(const float* __restrict__ W,
                                             const float* __restrict__ al,
                                             const float* __restrict__ ar,
                                             f16* __restrict__ out, int K, int layer) {
  int idx = blockIdx.x * 256 + threadIdx.x;
  if (idx >= 40 * K) return;
  int k = idx % K;
  int row = idx / K;
  int j = row >> 3, r = row & 7, h = r & 3, isr = r >> 2;
  const float* a = (isr ? ar : al) + (((size_t)layer * NETYPE + j) * NHEAD + h) * DHEAD;
  const float* w = W + ((size_t)j * K + k) * HIDC + h * DHEAD;
  float s = 0.f;
  for (int d = 0; d < DHEAD; d++) s += w[d] * a[d];
  out[idx] = (f16)s;
}

__global__ __launch_bounds__(256) void k_comb_bias(const float* __restrict__ skip_b,
                                                   const float* __restrict__ conv_bias,
                                                   float* __restrict__ outb, int layer) {
  int c = blockIdx.x * 256 + threadIdx.x;
  if (c < HIDC) {
    float v = skip_b[c];
    for (int j = 0; j < NETYPE; j++) v += conv_bias[(layer * NETYPE + j) * HIDC + c];
    outb[c] = v;
  }
}

// ---------------- CSR build ----------------

__global__ __launch_bounds__(256) void k_hist(const int* __restrict__ dst,
                                              int* __restrict__ deg) {
  int e = blockIdx.x * 256 + threadIdx.x;
  if (e < N_EDGES) atomicAdd(&deg[dst[e]], 1);
}

__global__ __launch_bounds__(1024) void k_scan(const int* __restrict__ deg,
                                               int* __restrict__ rowptr) {
  __shared__ int sm[1024];
  __shared__ int carry_s;
  int tid = threadIdx.x;
  if (tid == 0) carry_s = 0;
  __syncthreads();
  for (int base = 0; base < N_NODES; base += 1024) {
    int v = (base + tid < N_NODES) ? deg[base + tid] : 0;
    sm[tid] = v;
    __syncthreads();
    for (int off = 1; off < 1024; off <<= 1) {
      int t = (tid >= off) ? sm[tid - off] : 0;
      __syncthreads();
      sm[tid] += t;
      __syncthreads();
    }
    if (base + tid < N_NODES) rowptr[base + tid] = carry_s + sm[tid] - v;
    int tot = sm[1023];
    __syncthreads();
    if (tid == 0) carry_s += tot;
    __syncthreads();
  }
  if (tid == 0) rowptr[N_NODES] = carry_s;
}

__global__ __launch_bounds__(256) void k_scatter(const int* __restrict__ src,
                                                 const int* __restrict__ dst,
                                                 const int* __restrict__ et,
                                                 int* __restrict__ cursor,
                                                 int* __restrict__ packed) {
  int e = blockIdx.x * 256 + threadIdx.x;
  if (e < N_EDGES) {
    int pos = atomicAdd(&cursor[dst[e]], 1);
    packed[pos] = src[e] | (et[e] << 27);
  }
}

// ---------------- GEMM: C[M,Nc] = A[M,K](f16) @ Bt[Nc,K]^T(f16) + bias ----------------
// 128x128 block tile, BK=32, 4 waves in 2x2, each wave 64x64 via 4x4 mfma 16x16x32.

template <typename OT>
__global__ __launch_bounds__(256) void k_gemm(const f16* __restrict__ A,
                                              const f16* __restrict__ Bt,
                                              const float* __restrict__ bias,
                                              OT* __restrict__ C,
                                              int M, int Nc, int K, int ldc) {
  __shared__ f16 As[128 * 40];
  __shared__ f16 Bs[128 * 40];
  int tid = threadIdx.x;
  int bm = blockIdx.x * 128, bn = blockIdx.y * 128;
  int wave = tid >> 6, lane = tid & 63;
  int wm = (wave >> 1) * 64, wn = (wave & 1) * 64;
  int sr = tid >> 1, sq = (tid & 1) * 16;
  int arow_ok = (bm + sr) < M;
  int brow_ok = (bn + sr) < Nc;
  const f16* aptr = A + (size_t)(bm + sr) * K + sq;
  const f16* bptr = Bt + (size_t)(bn + sr) * K + sq;
  int frow = lane & 15, fk = (lane >> 4) * 8;
  f32x4 acc[4][4] = {};

  for (int k0 = 0; k0 < K; k0 += 32) {
    uint4 av0 = {0, 0, 0, 0}, av1 = {0, 0, 0, 0};
    uint4 bv0 = {0, 0, 0, 0}, bv1 = {0, 0, 0, 0};
    if (arow_ok) {
      av0 = *(const uint4*)(aptr + k0);
      av1 = *(const uint4*)(aptr + k0 + 8);
    }
    if (brow_ok) {
      bv0 = *(const uint4*)(bptr + k0);
      bv1 = *(const uint4*)(bptr + k0 + 8);
    }
    __syncthreads();
    *(uint4*)(As + sr * 40 + sq) = av0;
    *(uint4*)(As + sr * 40 + sq + 8) = av1;
    *(uint4*)(Bs + sr * 40 + sq) = bv0;
    *(uint4*)(Bs + sr * 40 + sq + 8) = bv1;
    __syncthreads();
    f16x8 af[4], bf[4];
#pragma unroll
    for (int mi = 0; mi < 4; mi++)
      af[mi] = *(const f16x8*)(As + (wm + mi * 16 + frow) * 40 + fk);
#pragma unroll
    for (int ni = 0; ni < 4; ni++)
      bf[ni] = *(const f16x8*)(Bs + (wn + ni * 16 + frow) * 40 + fk);
#pragma unroll
    for (int mi = 0; mi < 4; mi++)
#pragma unroll
      for (int ni = 0; ni < 4; ni++)
        acc[mi][ni] = __builtin_amdgcn_mfma_f32_16x16x32_f16(af[mi], bf[ni],
                                                             acc[mi][ni], 0, 0, 0);
  }

  int ccol = lane & 15, crow = (lane >> 4) * 4;
#pragma unroll
  for (int mi = 0; mi < 4; mi++) {
#pragma unroll
    for (int r = 0; r < 4; r++) {
      int rg = bm + wm + mi * 16 + crow + r;
      if (rg < M) {
#pragma unroll
        for (int ni = 0; ni < 4; ni++) {
          int cg = bn + wn + ni * 16 + ccol;
          if (cg < Nc)
            C[(size_t)rg * ldc + cg] = (OT)(acc[mi][ni][r] + (bias ? bias[cg] : 0.f));
        }
      }
    }
  }
}

// ---------------- fused per-dst aggregation: all 5 etypes, 2 heads (one half) ----------
// block = one dst node, 128 threads = 2 waves; wave wv handles head half*2+wv.
// elr[N][40] fp32: el at j*8+h, er at j*8+4+h. feat: f16 [N][5*256] for this half.

__global__ __launch_bounds__(128) void k_agg(const int* __restrict__ rowptr,
                                             const int* __restrict__ packed,
                                             const float* __restrict__ elr,
                                             const f16* __restrict__ feat,
                                             float* __restrict__ x_skip, int half) {
  int d = blockIdx.x;
  int beg = rowptr[d], end = rowptr[d + 1];
  if (beg == end) return;
  int wv = threadIdx.x >> 6, lane = threadIdx.x & 63;
  int head = half * 2 + wv;

  float erh[NETYPE], m[NETYPE], s[NETYPE];
#pragma unroll
  for (int j = 0; j < NETYPE; j++) {
    erh[j] = elr[(size_t)d * 40 + j * 8 + 4 + head];
    m[j] = -1e30f;
    s[j] = 0.f;
  }

  for (int p = beg; p < end; ++p) {
    int pk = packed[p];
    int et = pk >> 27;
    int sn = pk & 0x07FFFFFF;
    float elv = elr[(size_t)sn * 40 + et * 8 + head];
    float erv = 0.f;
#pragma unroll
    for (int j = 0; j < NETYPE; j++) erv = (et == j) ? erh[j] : erv;
    float e = elv + erv;
    e = (e > 0.f) ? e : 0.2f * e;
#pragma unroll
    for (int j = 0; j < NETYPE; j++) {
      bool hit = (et == j);
      float ej = hit ? e : -1e30f;
      float nm = fmaxf(m[j], ej);
      s[j] = s[j] * __expf(m[j] - nm) + (hit ? __expf(ej - nm) : 0.f);
      m[j] = nm;
    }
  }

  float inv[NETYPE];
#pragma unroll
  for (int j = 0; j < NETYPE; j++) inv[j] = (s[j] > 0.f) ? 1.f / s[j] : 0.f;

  float accx = 0.f, accy = 0.f;
  int c = wv * 128 + lane * 2;  // column within the half (0..255)
  for (int p = beg; p < end; ++p) {
    int pk = packed[p];
    int et = pk >> 27;
    int sn = pk & 0x07FFFFFF;
    float elv = elr[(size_t)sn * 40 + et * 8 + head];
    float erv = 0.f, mm = 0.f, iv = 0.f;
#pragma unroll
    for (int j = 0; j < NETYPE; j++) {
      bool hit = (et == j);
      erv = hit ? erh[j] : erv;
      mm = hit ? m[j] : mm;
      iv = hit ? inv[j] : iv;
    }
    float e = elv + erv;
    e = (e > 0.f) ? e : 0.2f * e;
    float alpha = __expf(e - mm) * iv;
    f16x2 f = *(const f16x2*)(feat + (size_t)sn * FEATW + et * 256 + c);
    accx += alpha * (float)f.x;
    accy += alpha * (float)f.y;
  }

  float2* xp = (float2*)(x_skip + (size_t)d * HIDC + head * DHEAD + lane * 2);
  float2 v = *xp;
  v.x += accx;
  v.y += accy;
  *xp = v;
}

// ---------------- batch norm ----------------

__global__ __launch_bounds__(256) void k_bn_reduce(const float* __restrict__ x,
                                                   float* __restrict__ gsum,
                                                   float* __restrict__ gsq) {
  int t = threadIdx.x;
  float sx = 0.f, sy = 0.f, qx = 0.f, qy = 0.f;
  for (int r = blockIdx.x; r < N_NODES; r += gridDim.x) {
    float2 v = *(const float2*)(x + (size_t)r * HIDC + t * 2);
    sx += v.x; sy += v.y;
    qx += v.x * v.x; qy += v.y * v.y;
  }
  atomicAdd(&gsum[t * 2], sx);
  atomicAdd(&gsum[t * 2 + 1], sy);
  atomicAdd(&gsq[t * 2], qx);
  atomicAdd(&gsq[t * 2 + 1], qy);
}

__global__ __launch_bounds__(256) void k_bn_final(const float* __restrict__ gsum,
                                                  const float* __restrict__ gsq,
                                                  const float* __restrict__ gamma,
                                                  const float* __restrict__ beta,
                                                  float* __restrict__ scale,
                                                  float* __restrict__ shift) {
  int c = blockIdx.x * 256 + threadIdx.x;
  if (c < HIDC) {
    float mu = gsum[c] * (1.f / N_NODES);
    float var = gsq[c] * (1.f / N_NODES) - mu * mu;
    float sc = gamma[c] * rsqrtf(var + 1e-5f);
    scale[c] = sc;
    shift[c] = beta[c] - mu * sc;
  }
}

// act==0: ELU, act==1: ReLU; writes f16 (next GEMM input)
__global__ __launch_bounds__(256) void k_bn_apply(const float* __restrict__ x,
                                                  const float* __restrict__ scale,
                                                  const float* __restrict__ shift,
                                                  f16* __restrict__ out, int act) {
  long i = ((long)blockIdx.x * blockDim.x + threadIdx.x) * 2;
  if (i >= (long)N_NODES * HIDC) return;
  int c = (int)(i & (HIDC - 1));
  float2 v = *(const float2*)(x + i);
  float a0 = scale[c] * v.x + shift[c];
  float a1 = scale[c + 1] * v.y + shift[c + 1];
  if (act == 0) {
    a0 = a0 > 0.f ? a0 : expm1f(a0);
    a1 = a1 > 0.f ? a1 : expm1f(a1);
  } else {
    a0 = fmaxf(a0, 0.f);
    a1 = fmaxf(a1, 0.f);
  }
  f16x2 o = { (f16)a0, (f16)a1 };
  *(f16x2*)(out + i) = o;
}

// ---------------- launch ----------------

extern "C" void kernel_launch(void* const* d_in, const int* in_sizes, int n_in,
                              void* d_out, int out_size, void* d_ws, size_t ws_size,
                              hipStream_t stream) {
  const float* x = (const float*)d_in[0];
  const int* src = (const int*)d_in[1];
  const int* dst = (const int*)d_in[2];
  const int* etype = (const int*)d_in[3];
  const float* W0 = (const float*)d_in[4];
  const float* W1 = (const float*)d_in[5];
  const float* attn_l = (const float*)d_in[6];
  const float* attn_r = (const float*)d_in[7];
  const float* conv_bias = (const float*)d_in[8];
  const float* skip_W0 = (const float*)d_in[9];
  const float* skip_b0 = (const float*)d_in[10];
  const float* skip_W1 = (const float*)d_in[11];
  const float* skip_b1 = (const float*)d_in[12];
  const float* norm_gamma = (const float*)d_in[13];
  const float* norm_beta = (const float*)d_in[14];
  const float* mlp_W1 = (const float*)d_in[15];
  const float* mlp_b1 = (const float*)d_in[16];
  const float* mlp_g = (const float*)d_in[17];
  const float* mlp_bt = (const float*)d_in[18];
  const float* mlp_W2 = (const float*)d_in[19];
  const float* mlp_b2 = (const float*)d_in[20];
  float* out = (float*)d_out;

  char* ws = (char*)d_ws;
  size_t off = 0;
  auto alloc = [&](size_t bytes) {
    void* p = ws + off;
    off = (off + bytes + 255) & ~(size_t)255;
    return p;
  };
  float* x_skip = (float*)alloc((size_t)N_NODES * HIDC * 4);
  f16*   feat_h = (f16*)alloc((size_t)N_NODES * FEATW * 2);  // also reused fp32 for MLP
  f16*   hb     = (f16*)alloc((size_t)N_NODES * IN_CH * 2);
  float* elr    = (float*)alloc((size_t)N_NODES * 40 * 4);
  int*   deg    = (int*)alloc((size_t)N_NODES * 4);
  int*   rowptr = (int*)alloc((size_t)(N_NODES + 1) * 4);
  int*   cursor = (int*)alloc((size_t)N_NODES * 4);
  int*   packed = (int*)alloc((size_t)N_EDGES * 4);
  f16* Wt0h0 = (f16*)alloc((size_t)FEATW * IN_CH * 2);
  f16* Wt0h1 = (f16*)alloc((size_t)FEATW * IN_CH * 2);
  f16* Wt1h0 = (f16*)alloc((size_t)FEATW * HIDC * 2);
  f16* Wt1h1 = (f16*)alloc((size_t)FEATW * HIDC * 2);
  f16* sW0t = (f16*)alloc((size_t)HIDC * IN_CH * 2);
  f16* sW1t = (f16*)alloc((size_t)HIDC * HIDC * 2);
  f16* m1t  = (f16*)alloc((size_t)HIDC * HIDC * 2);
  f16* m2t  = (f16*)alloc((size_t)OUT_CH * HIDC * 2);
  f16* wlr0 = (f16*)alloc((size_t)40 * IN_CH * 2);
  f16* wlr1 = (f16*)alloc((size_t)40 * HIDC * 2);
  float* bias0 = (float*)alloc(HIDC * 4);
  float* bias1 = (float*)alloc(HIDC * 4);
  float* gsum  = (float*)alloc(HIDC * 4);
  float* gsq   = (float*)alloc(HIDC * 4);
  float* scale = (float*)alloc(HIDC * 4);
  float* shift = (float*)alloc(HIDC * 4);
  float* feat32 = (float*)feat_h;  // MLP intermediate (fp32 N x 512 fits)

  // ---- CSR build ----
  hipMemsetAsync(deg, 0, (size_t)N_NODES * 4, stream);
  k_hist<<<cdiv(N_EDGES, 256), 256, 0, stream>>>(dst, deg);
  k_scan<<<1, 1024, 0, stream>>>(deg, rowptr);
  hipMemcpyAsync(cursor, rowptr, (size_t)N_NODES * 4, hipMemcpyDeviceToDevice, stream);
  k_scatter<<<cdiv(N_EDGES, 256), 256, 0, stream>>>(src, dst, etype, cursor, packed);

  // ---- weight prep ----
  k_transpose_stack<<<cdiv(NETYPE * 256 * IN_CH, 256), 256, 0, stream>>>(W0, Wt0h0, IN_CH, 0);
  k_transpose_stack<<<cdiv(NETYPE * 256 * IN_CH, 256), 256, 0, stream>>>(W0, Wt0h1, IN_CH, 256);
  k_transpose_stack<<<cdiv(NETYPE * 256 * HIDC, 256), 256, 0, stream>>>(W1, Wt1h0, HIDC, 0);
  k_transpose_stack<<<cdiv(NETYPE * 256 * HIDC, 256), 256, 0, stream>>>(W1, Wt1h1, HIDC, 256);
  k_transpose_cvt<<<cdiv(IN_CH * HIDC, 256), 256, 0, stream>>>(skip_W0, sW0t, IN_CH, HIDC);
  k_transpose_cvt<<<cdiv(HIDC * HIDC, 256), 256, 0, stream>>>(skip_W1, sW1t, HIDC, HIDC);
  k_transpose_cvt<<<cdiv(HIDC * HIDC, 256), 256, 0, stream>>>(mlp_W1, m1t, HIDC, HIDC);
  k_transpose_cvt<<<cdiv(HIDC * OUT_CH, 256), 256, 0, stream>>>(mlp_W2, m2t, HIDC, OUT_CH);
  k_wlr<<<cdiv(40 * IN_CH, 256), 256, 0, stream>>>(W0, attn_l, attn_r, wlr0, IN_CH, 0);
  k_wlr<<<cdiv(40 * HIDC, 256), 256, 0, stream>>>(W1, attn_l, attn_r, wlr1, HIDC, 1);
  k_comb_bias<<<2, 256, 0, stream>>>(skip_b0, conv_bias, bias0, 0);
  k_comb_bias<<<2, 256, 0, stream>>>(skip_b1, conv_bias, bias1, 1);

  // ---- x -> f16 ----
  k_cvt_f16<<<cdiv(N_NODES * IN_CH / 4, 256), 256, 0, stream>>>(x, hb, (long)N_NODES * IN_CH);

  const int gm = cdiv(N_NODES, 128);

  for (int layer = 0; layer < 2; layer++) {
    int K = layer ? HIDC : IN_CH;
    const f16* skipt = layer ? sW1t : sW0t;
    const f16* wlr = layer ? wlr1 : wlr0;
    const f16* Wh[2] = { layer ? Wt1h0 : Wt0h0, layer ? Wt1h1 : Wt0h1 };
    const float* biasL = layer ? bias1 : bias0;

    // x_skip = hb @ skipW + (skip_b + sum_j conv_bias)
    k_gemm<float><<<dim3(gm, 4), 256, 0, stream>>>(hb, skipt, biasL, x_skip,
                                                   N_NODES, HIDC, K, HIDC);
    // all attention scores: elr = hb @ wlr  [N,40]
    k_gemm<float><<<dim3(gm, 1), 256, 0, stream>>>(hb, wlr, nullptr, elr,
                                                   N_NODES, 40, K, 40);
    for (int half = 0; half < 2; half++) {
      k_gemm<f16><<<dim3(gm, FEATW / 128), 256, 0, stream>>>(hb, Wh[half], nullptr, feat_h,
                                                             N_NODES, FEATW, K, FEATW);
      k_agg<<<N_NODES, 128, 0, stream>>>(rowptr, packed, elr, feat_h, x_skip, half);
    }

    hipMemsetAsync(gsum, 0, HIDC * 4, stream);
    hipMemsetAsync(gsq, 0, HIDC * 4, stream);
    k_bn_reduce<<<512, 256, 0, stream>>>(x_skip, gsum, gsq);
    k_bn_final<<<2, 256, 0, stream>>>(gsum, gsq, norm_gamma + layer * HIDC,
                                      norm_beta + layer * HIDC, scale, shift);
    k_bn_apply<<<cdiv(N_NODES * HIDC / 2, 256), 256, 0, stream>>>(x_skip, scale, shift, hb, 0);
  }

  // ---- MLP head ----
  k_gemm<float><<<dim3(gm, 4), 256, 0, stream>>>(hb, m1t, mlp_b1, feat32,
                                                 N_NODES, HIDC, HIDC, HIDC);
  hipMemsetAsync(gsum, 0, HIDC * 4, stream);
  hipMemsetAsync(gsq, 0, HIDC * 4, stream);
  k_bn_reduce<<<512, 256, 0, stream>>>(feat32, gsum, gsq);
  k_bn_final<<<2, 256, 0, stream>>>(gsum, gsq, mlp_g, mlp_bt, scale, shift);
  k_bn_apply<<<cdiv(N_NODES * HIDC / 2, 256), 256, 0, stream>>>(feat32, scale, shift, hb, 1);
  k_gemm<float><<<dim3(gm, cdiv(OUT_CH, 128)), 256, 0, stream>>>(hb, m2t, mlp_b2, out,
                                                                 N_NODES, OUT_CH, HIDC, OUT_CH);
}